// Round 16
// baseline (100.909 us; speedup 1.0000x reference)
//
#include <hip/hip_runtime.h>
#include <math.h>

#define NN 4096
#define NB 4
#define NITER 10
#define ROWS 16            // rows per block (matvec)
#define TW 512             // 8 waves per block (matvec)
#define HT 128             // head tile size
#define HBLK 528           // 32*33/2 triangular tile pairs

typedef _Float16 f16x8 __attribute__((ext_vector_type(8)));
typedef float f32x4 __attribute__((ext_vector_type(4)));

// persistent scratch in module .bss — fully rewritten every call (deterministic)
__device__ __align__(16) float gA [NB * NN];
__device__ __align__(16) float gUx[NB * NN];
__device__ __align__(16) float gUy[NB * NN];
__device__ __align__(16) unsigned short gTh[2][12 * NN]; // ping-pong T^T as f16: [c][m]

__device__ inline unsigned short f16b(float x) {
    _Float16 h = (_Float16)x;
    return *(unsigned short*)&h;
}

// ---- merged head: blocks [0,528) symmetrize W -> f16 (128x128 tile pairs);
//      blocks [528,560) stats + T^T(iter0) ----
__global__ __launch_bounds__(512) void head_kernel(const float* __restrict__ W,
    unsigned short* __restrict__ Sb16, const float* __restrict__ dp,
    const float* __restrict__ logits) {
    if (blockIdx.x >= HBLK) {
        int i = (blockIdx.x - HBLK) * 512 + threadIdx.x;          // 0..16383
        int b = i >> 12, n = i & 4095;
        float x = dp[2 * i], y = dp[2 * i + 1];
        float sq = x * x + y * y;
        float av = expf(-0.5f * sq);
        float inv = 1.0f / sqrtf(sq);
        float uxv = x * inv, uyv = y * inv;
        gA[i] = av; gUx[i] = uxv; gUy[i] = uyv;
        float l = logits[i];
        float mv = 2.0f / (1.0f + expf(-l)) - 1.0f;
        float t0 = av * mv;
        gTh[0][(3 * b + 0) * NN + n] = f16b(t0);
        gTh[0][(3 * b + 1) * NN + n] = f16b(t0 * uxv);
        gTh[0][(3 * b + 2) * NN + n] = f16b(t0 * uyv);
        return;
    }
    __shared__ float At[HT][HT + 1];                 // 64.5 KB
    __shared__ float Bt[HT][HT + 1];                 // 64.5 KB
    int idx = blockIdx.x, bi = 0, rem = 32;
    while (idx >= rem) { idx -= rem; ++bi; --rem; }
    int bj = bi + idx;
    {
        int row = threadIdx.x >> 5;                  // 0..15
        int c4 = (threadIdx.x & 31) * 4;             // float col (x4)
#pragma unroll
        for (int i = 0; i < 8; ++i) {
            int r = row + i * 16;
            float4 va = *(const float4*)&W[(size_t)(bi * HT + r) * NN + bj * HT + c4];
            float4 vb = *(const float4*)&W[(size_t)(bj * HT + r) * NN + bi * HT + c4];
            At[r][c4 + 0] = va.x; At[r][c4 + 1] = va.y;
            At[r][c4 + 2] = va.z; At[r][c4 + 3] = va.w;
            Bt[r][c4 + 0] = vb.x; Bt[r][c4 + 1] = vb.y;
            Bt[r][c4 + 2] = vb.z; Bt[r][c4 + 3] = vb.w;
        }
    }
    __syncthreads();
    {
        int c = threadIdx.x & 127;                   // column (stride-129 LDS reads)
        int rq = threadIdx.x >> 7;                   // 0..3
#pragma unroll
        for (int i = 0; i < 32; ++i) {
            int r = rq + i * 4;
            float v = 0.5f * (At[r][c] + Bt[c][r]);
            float u = 0.5f * (Bt[r][c] + At[c][r]);
            Sb16[(size_t)(bi * HT + r) * NN + bj * HT + c] = f16b(v);
            Sb16[(size_t)(bj * HT + r) * NN + bi * HT + c] = f16b(u);
        }
    }
}

// ---- fused MFMA matvec + update: block owns 16 rows x full K ----
// (verbatim R15 — passing.)  Per-wave T staging into private LDS slice; no
// block barrier before MFMA.  A: lane&15=row, 8 consecutive k.  B: lane&15=col,
// 8 consecutive k.  D: col=lane&15, row=(lane>>4)*4+reg  [verified m91 mapping].
__global__ void __launch_bounds__(TW) matvec_kernel(const unsigned short* __restrict__ Wh,
    const float* __restrict__ logits, float* __restrict__ out, int rd, int last) {
    __shared__ __align__(16) unsigned short Tl[8][12 * 512]; // 96 KB, per-wave slices
    __shared__ __align__(16) float Ered[8][64][4];           // 8 KB
    __shared__ float El[16][17];

    const int tid = threadIdx.x;
    const int w = tid >> 6, lane = tid & 63;
    const int mrow = lane & 15, grp = lane >> 4;
    const int row0 = blockIdx.x * ROWS;
    const int kbase = w * 512;                             // K-eighth per wave
    const unsigned short* Wp = Wh + (size_t)(row0 + mrow) * NN + kbase + grp * 8;
    const int cc = mrow;                                   // B col for this lane
    const bool cok = (cc < 12);
    const unsigned short* Tcur = gTh[rd];

    // ---- prefetch all 16 A-fragments (W stream starts immediately) ----
    f16x8 areg[16];
#pragma unroll
    for (int mf = 0; mf < 16; ++mf) areg[mf] = *(const f16x8*)(Wp + mf * 32);

    // ---- per-wave stage of own T slice: granule (c,j) -> (c*64+j)^(c&7) ----
    unsigned short* Tw = &Tl[w][0];
#pragma unroll
    for (int c = 0; c < 12; ++c) {
        uint4 v = *(const uint4*)(Tcur + c * NN + kbase + lane * 8);
        int g = (c * 64 + lane) ^ (c & 7);
        *(uint4*)(Tw + g * 8) = v;
    }

    f32x4 acc = {0.f, 0.f, 0.f, 0.f};
#pragma unroll
    for (int mf = 0; mf < 16; ++mf) {                      // 16 MFMAs, k step 32
        f16x8 b = {};
        if (cok) {
            int g = (cc * 64 + mf * 4 + grp) ^ (cc & 7);
            b = *(const f16x8*)(Tw + g * 8);
        }
        acc = __builtin_amdgcn_mfma_f32_16x16x32_f16(areg[mf], b, acc, 0, 0, 0);
    }
    *(f32x4*)Ered[w][lane] = acc;
    __syncthreads();

    // ---- reduce 8 waves, scatter to El[row][col] ----
    if (tid < 64) {
        f32x4 s = {};
#pragma unroll
        for (int ww = 0; ww < 8; ++ww) s += *(const f32x4*)Ered[ww][tid];
        int rr = tid >> 4, c = tid & 15;
#pragma unroll
        for (int r = 0; r < 4; ++r) El[rr * 4 + r][c] = s[r];
    }
    __syncthreads();

    // ---- fused update / final output for this block's 16 rows ----
    if (tid < 64) {
        int b = tid >> 4, r = tid & 15;
        int m = row0 + r, idx = b * NN + m;
        float S0 = El[r][3 * b], S1 = El[r][3 * b + 1], S2 = El[r][3 * b + 2];
        float av = gA[idx], uxv = gUx[idx], uyv = gUy[idx];
        float l = logits[idx] + av * (S0 - uxv * S1 - uyv * S2);
        if (last) {
            out[idx] = l;
        } else {
            float mv = 2.0f / (1.0f + expf(-l)) - 1.0f;
            float t0 = av * mv;
            unsigned short* Td = gTh[rd ^ 1];
            Td[(3 * b + 0) * NN + m] = f16b(t0);
            Td[(3 * b + 1) * NN + m] = f16b(t0 * uxv);
            Td[(3 * b + 2) * NN + m] = f16b(t0 * uyv);
        }
    }
}

extern "C" void kernel_launch(void* const* d_in, const int* in_sizes, int n_in,
                              void* d_out, int out_size, void* d_ws, size_t ws_size,
                              hipStream_t stream) {
    const float* delta_p = (const float*)d_in[0];   // (4,64,64,2)
    const float* logits  = (const float*)d_in[1];   // (4,4096,1)
    const float* W       = (const float*)d_in[2];   // (1,4096,4096)
    float* out = (float*)d_out;

    unsigned short* Sb16 = (unsigned short*)d_ws;    // 32 MiB packed f16 Wsym
    const unsigned short* Wh = (const unsigned short*)d_ws;

    head_kernel<<<HBLK + 32, 512, 0, stream>>>(W, Sb16, delta_p, logits);

    for (int it = 0; it < NITER; ++it)
        matvec_kernel<<<256, TW, 0, stream>>>(Wh, logits, out, it & 1,
                                              it == NITER - 1 ? 1 : 0);
}

// Round 17
// 100.842 us; speedup vs baseline: 1.0007x; 1.0007x over previous
//
#include <hip/hip_runtime.h>
#include <math.h>

#define NN 4096
#define NB 4
#define NITER 10
#define ROWS 16            // rows per block (matvec)
#define TW 512             // 8 waves per block (matvec)
#define WSYM_BLOCKS 2080   // 64*65/2 triangular tile pairs

typedef _Float16 f16x8 __attribute__((ext_vector_type(8)));
typedef float f32x4 __attribute__((ext_vector_type(4)));

// persistent scratch in module .bss — fully rewritten every call (deterministic)
__device__ __align__(16) float gA [NB * NN];
__device__ __align__(16) float gUx[NB * NN];
__device__ __align__(16) float gUy[NB * NN];
__device__ __align__(16) unsigned short gTh[2][12 * NN]; // ping-pong T^T as f16: [c][m]

__device__ inline unsigned short f16b(float x) {
    _Float16 h = (_Float16)x;
    return *(unsigned short*)&h;
}
__device__ inline unsigned f16pair(float x, float y) {
    return (unsigned)f16b(x) | ((unsigned)f16b(y) << 16);
}

// ---- merged head: blocks [0,2080) symmetrize W -> f16 (64x64 tile pairs,
//      R15 shape); blocks [2080,2144) stats + T^T(iter0).
//      Non-temporal W loads + Wsym stores: pure stream, zero reuse -> keep L2 clean.
__global__ __launch_bounds__(256) void head_kernel(const float* __restrict__ W,
    unsigned* __restrict__ Sb, const float* __restrict__ dp,
    const float* __restrict__ logits) {
    if (blockIdx.x >= WSYM_BLOCKS) {
        // ---- stats + T^T(iter0) ----
        int i = (blockIdx.x - WSYM_BLOCKS) * 256 + threadIdx.x;   // 0..16383
        int b = i >> 12, n = i & 4095;
        float x = dp[2 * i], y = dp[2 * i + 1];
        float sq = x * x + y * y;
        float av = expf(-0.5f * sq);
        float inv = 1.0f / sqrtf(sq);
        float uxv = x * inv, uyv = y * inv;
        gA[i] = av; gUx[i] = uxv; gUy[i] = uyv;
        float l = logits[i];
        float mv = 2.0f / (1.0f + expf(-l)) - 1.0f;
        float t0 = av * mv;
        gTh[0][(3 * b + 0) * NN + n] = f16b(t0);
        gTh[0][(3 * b + 1) * NN + n] = f16b(t0 * uxv);
        gTh[0][(3 * b + 2) * NN + n] = f16b(t0 * uyv);
        return;
    }
    // ---- W_sym = (W+W^T)/2 -> packed f16 pairs; triangular tile pairs ----
    __shared__ float At[64][65];
    __shared__ float Bt[64][65];
    int idx = blockIdx.x, bi = 0, rem = 64;
    while (idx >= rem) { idx -= rem; ++bi; --rem; }
    int bj = bi + idx;
    int r0 = threadIdx.x >> 4;                       // 0..15
    int c4 = (threadIdx.x & 15) * 4;                 // float col (x4)
#pragma unroll
    for (int i = 0; i < 4; ++i) {
        int r = r0 + i * 16;
        f32x4 va = __builtin_nontemporal_load(
            (const f32x4*)&W[(size_t)(bi * 64 + r) * NN + bj * 64 + c4]);
        f32x4 vb = __builtin_nontemporal_load(
            (const f32x4*)&W[(size_t)(bj * 64 + r) * NN + bi * 64 + c4]);
        At[r][c4 + 0] = va.x; At[r][c4 + 1] = va.y;
        At[r][c4 + 2] = va.z; At[r][c4 + 3] = va.w;
        Bt[r][c4 + 0] = vb.x; Bt[r][c4 + 1] = vb.y;
        Bt[r][c4 + 2] = vb.z; Bt[r][c4 + 3] = vb.w;
    }
    __syncthreads();
    int tp = threadIdx.x & 31;                       // column-pair index
    int rr = threadIdx.x >> 5;                       // 0..7
#pragma unroll
    for (int i = 0; i < 8; ++i) {
        int r = rr + i * 8;
        int c0 = 2 * tp, c1 = c0 + 1;
        float v0 = 0.5f * (At[r][c0] + Bt[c0][r]);
        float v1 = 0.5f * (At[r][c1] + Bt[c1][r]);
        __builtin_nontemporal_store(f16pair(v0, v1),
            &Sb[(size_t)(bi * 64 + r) * 2048 + bj * 32 + tp]);
        float u0 = 0.5f * (Bt[r][c0] + At[c0][r]);
        float u1 = 0.5f * (Bt[r][c1] + At[c1][r]);
        __builtin_nontemporal_store(f16pair(u0, u1),
            &Sb[(size_t)(bj * 64 + r) * 2048 + bi * 32 + tp]);
    }
}

// ---- fused MFMA matvec + update: block owns 16 rows x full K ----
// (verbatim R15 — passing.)  Per-wave T staging into private LDS slice; no
// block barrier before MFMA.  A: lane&15=row, 8 consecutive k.  B: lane&15=col,
// 8 consecutive k.  D: col=lane&15, row=(lane>>4)*4+reg  [verified m91 mapping].
__global__ void __launch_bounds__(TW) matvec_kernel(const unsigned short* __restrict__ Wh,
    const float* __restrict__ logits, float* __restrict__ out, int rd, int last) {
    __shared__ __align__(16) unsigned short Tl[8][12 * 512]; // 96 KB, per-wave slices
    __shared__ __align__(16) float Ered[8][64][4];           // 8 KB
    __shared__ float El[16][17];

    const int tid = threadIdx.x;
    const int w = tid >> 6, lane = tid & 63;
    const int mrow = lane & 15, grp = lane >> 4;
    const int row0 = blockIdx.x * ROWS;
    const int kbase = w * 512;                             // K-eighth per wave
    const unsigned short* Wp = Wh + (size_t)(row0 + mrow) * NN + kbase + grp * 8;
    const int cc = mrow;                                   // B col for this lane
    const bool cok = (cc < 12);
    const unsigned short* Tcur = gTh[rd];

    // ---- prefetch all 16 A-fragments (W stream starts immediately) ----
    f16x8 areg[16];
#pragma unroll
    for (int mf = 0; mf < 16; ++mf) areg[mf] = *(const f16x8*)(Wp + mf * 32);

    // ---- per-wave stage of own T slice: granule (c,j) -> (c*64+j)^(c&7) ----
    unsigned short* Tw = &Tl[w][0];
#pragma unroll
    for (int c = 0; c < 12; ++c) {
        uint4 v = *(const uint4*)(Tcur + c * NN + kbase + lane * 8);
        int g = (c * 64 + lane) ^ (c & 7);
        *(uint4*)(Tw + g * 8) = v;
    }

    f32x4 acc = {0.f, 0.f, 0.f, 0.f};
#pragma unroll
    for (int mf = 0; mf < 16; ++mf) {                      // 16 MFMAs, k step 32
        f16x8 b = {};
        if (cok) {
            int g = (cc * 64 + mf * 4 + grp) ^ (cc & 7);
            b = *(const f16x8*)(Tw + g * 8);
        }
        acc = __builtin_amdgcn_mfma_f32_16x16x32_f16(areg[mf], b, acc, 0, 0, 0);
    }
    *(f32x4*)Ered[w][lane] = acc;
    __syncthreads();

    // ---- reduce 8 waves, scatter to El[row][col] ----
    if (tid < 64) {
        f32x4 s = {};
#pragma unroll
        for (int ww = 0; ww < 8; ++ww) s += *(const f32x4*)Ered[ww][tid];
        int rr = tid >> 4, c = tid & 15;
#pragma unroll
        for (int r = 0; r < 4; ++r) El[rr * 4 + r][c] = s[r];
    }
    __syncthreads();

    // ---- fused update / final output for this block's 16 rows ----
    if (tid < 64) {
        int b = tid >> 4, r = tid & 15;
        int m = row0 + r, idx = b * NN + m;
        float S0 = El[r][3 * b], S1 = El[r][3 * b + 1], S2 = El[r][3 * b + 2];
        float av = gA[idx], uxv = gUx[idx], uyv = gUy[idx];
        float l = logits[idx] + av * (S0 - uxv * S1 - uyv * S2);
        if (last) {
            out[idx] = l;
        } else {
            float mv = 2.0f / (1.0f + expf(-l)) - 1.0f;
            float t0 = av * mv;
            unsigned short* Td = gTh[rd ^ 1];
            Td[(3 * b + 0) * NN + m] = f16b(t0);
            Td[(3 * b + 1) * NN + m] = f16b(t0 * uxv);
            Td[(3 * b + 2) * NN + m] = f16b(t0 * uyv);
        }
    }
}

extern "C" void kernel_launch(void* const* d_in, const int* in_sizes, int n_in,
                              void* d_out, int out_size, void* d_ws, size_t ws_size,
                              hipStream_t stream) {
    const float* delta_p = (const float*)d_in[0];   // (4,64,64,2)
    const float* logits  = (const float*)d_in[1];   // (4,4096,1)
    const float* W       = (const float*)d_in[2];   // (1,4096,4096)
    float* out = (float*)d_out;

    unsigned* Wb = (unsigned*)d_ws;                  // 32 MiB packed f16 Wsym
    const unsigned short* Wh = (const unsigned short*)d_ws;

    head_kernel<<<WSYM_BLOCKS + 64, 256, 0, stream>>>(W, Wb, delta_p, logits);

    for (int it = 0; it < NITER; ++it)
        matvec_kernel<<<256, TW, 0, stream>>>(Wh, logits, out, it & 1,
                                              it == NITER - 1 ? 1 : 0);
}

// Round 18
// 96.946 us; speedup vs baseline: 1.0409x; 1.0402x over previous
//
#include <hip/hip_runtime.h>
#include <math.h>

#define NN 4096
#define NB 4
#define NITER 10
#define ROWS 16            // rows per block (matvec)
#define TW 512             // 8 waves per block (matvec)
#define WSYM_BLOCKS 2080   // 64*65/2 triangular tile pairs

typedef _Float16 f16x8 __attribute__((ext_vector_type(8)));
typedef float f32x4 __attribute__((ext_vector_type(4)));

// persistent scratch in module .bss — fully rewritten every call (deterministic)
__device__ __align__(16) float gA [NB * NN];
__device__ __align__(16) float gUx[NB * NN];
__device__ __align__(16) float gUy[NB * NN];
__device__ __align__(16) unsigned short gTh[2][12 * NN]; // ping-pong T^T as f16: [c][m]

__device__ inline unsigned short f16b(float x) {
    _Float16 h = (_Float16)x;
    return *(unsigned short*)&h;
}
__device__ inline unsigned f16pair(float x, float y) {
    return (unsigned)f16b(x) | ((unsigned)f16b(y) << 16);
}

// ---- merged head: blocks [0,2080) symmetrize W -> f16; blocks [2080,2144) stats ----
__global__ __launch_bounds__(256) void head_kernel(const float* __restrict__ W,
    unsigned* __restrict__ Sb, const float* __restrict__ dp,
    const float* __restrict__ logits) {
    if (blockIdx.x >= WSYM_BLOCKS) {
        // ---- stats + T^T(iter0) ----
        int i = (blockIdx.x - WSYM_BLOCKS) * 256 + threadIdx.x;   // 0..16383
        int b = i >> 12, n = i & 4095;
        float x = dp[2 * i], y = dp[2 * i + 1];
        float sq = x * x + y * y;
        float av = expf(-0.5f * sq);
        float inv = 1.0f / sqrtf(sq);
        float uxv = x * inv, uyv = y * inv;
        gA[i] = av; gUx[i] = uxv; gUy[i] = uyv;
        float l = logits[i];
        float mv = 2.0f / (1.0f + expf(-l)) - 1.0f;
        float t0 = av * mv;
        gTh[0][(3 * b + 0) * NN + n] = f16b(t0);
        gTh[0][(3 * b + 1) * NN + n] = f16b(t0 * uxv);
        gTh[0][(3 * b + 2) * NN + n] = f16b(t0 * uyv);
        return;
    }
    // ---- W_sym = (W+W^T)/2 -> packed f16 pairs; triangular tile pairs ----
    __shared__ float At[64][65];
    __shared__ float Bt[64][65];
    int idx = blockIdx.x, bi = 0, rem = 64;
    while (idx >= rem) { idx -= rem; ++bi; --rem; }
    int bj = bi + idx;
    int r0 = threadIdx.x >> 4;                       // 0..15
    int c4 = (threadIdx.x & 15) * 4;                 // float col (x4)
#pragma unroll
    for (int i = 0; i < 4; ++i) {
        int r = r0 + i * 16;
        float4 va = *(const float4*)&W[(size_t)(bi * 64 + r) * NN + bj * 64 + c4];
        float4 vb = *(const float4*)&W[(size_t)(bj * 64 + r) * NN + bi * 64 + c4];
        At[r][c4 + 0] = va.x; At[r][c4 + 1] = va.y;
        At[r][c4 + 2] = va.z; At[r][c4 + 3] = va.w;
        Bt[r][c4 + 0] = vb.x; Bt[r][c4 + 1] = vb.y;
        Bt[r][c4 + 2] = vb.z; Bt[r][c4 + 3] = vb.w;
    }
    __syncthreads();
    int tp = threadIdx.x & 31;                       // column-pair index
    int rr = threadIdx.x >> 5;                       // 0..7
#pragma unroll
    for (int i = 0; i < 8; ++i) {
        int r = rr + i * 8;
        int c0 = 2 * tp, c1 = c0 + 1;
        float v0 = 0.5f * (At[r][c0] + Bt[c0][r]);
        float v1 = 0.5f * (At[r][c1] + Bt[c1][r]);
        Sb[(size_t)(bi * 64 + r) * 2048 + bj * 32 + tp] = f16pair(v0, v1);
        float u0 = 0.5f * (Bt[r][c0] + At[c0][r]);
        float u1 = 0.5f * (Bt[r][c1] + At[c1][r]);
        Sb[(size_t)(bj * 64 + r) * 2048 + bi * 32 + tp] = f16pair(u0, u1);
    }
}

// ---- fused MFMA matvec + update: block owns 16 rows x full K ----
// Per-wave T staging: wave w consumes only k in [w*512, w*512+512) — stage that
// 12 KB slice into a wave-PRIVATE LDS region. No block barrier before MFMA
// (wave-synchronous ds_write -> ds_read; compiler emits the lgkmcnt wait).
// A-fragments prefetched to registers first so the W stream is in flight from
// cycle 0.  A: lane&15=row, 8 consecutive k.  B: lane&15=col, 8 consecutive k.
// D: col=lane&15, row=(lane>>4)*4+reg  [verified m91 mapping, R10/R13 passing].
__global__ void __launch_bounds__(TW) matvec_kernel(const unsigned short* __restrict__ Wh,
    const float* __restrict__ logits, float* __restrict__ out, int rd, int last) {
    __shared__ __align__(16) unsigned short Tl[8][12 * 512]; // 96 KB, per-wave slices
    __shared__ __align__(16) float Ered[8][64][4];           // 8 KB
    __shared__ float El[16][17];

    const int tid = threadIdx.x;
    const int w = tid >> 6, lane = tid & 63;
    const int mrow = lane & 15, grp = lane >> 4;
    const int row0 = blockIdx.x * ROWS;
    const int kbase = w * 512;                             // K-eighth per wave
    const unsigned short* Wp = Wh + (size_t)(row0 + mrow) * NN + kbase + grp * 8;
    const int cc = mrow;                                   // B col for this lane
    const bool cok = (cc < 12);
    const unsigned short* Tcur = gTh[rd];

    // ---- prefetch all 16 A-fragments (W stream starts immediately) ----
    f16x8 areg[16];
#pragma unroll
    for (int mf = 0; mf < 16; ++mf) areg[mf] = *(const f16x8*)(Wp + mf * 32);

    // ---- per-wave stage of own T slice: granule (c,j) -> (c*64+j)^(c&7) ----
    unsigned short* Tw = &Tl[w][0];
#pragma unroll
    for (int c = 0; c < 12; ++c) {
        uint4 v = *(const uint4*)(Tcur + c * NN + kbase + lane * 8);
        int g = (c * 64 + lane) ^ (c & 7);
        *(uint4*)(Tw + g * 8) = v;
    }

    f32x4 acc = {0.f, 0.f, 0.f, 0.f};
#pragma unroll
    for (int mf = 0; mf < 16; ++mf) {                      // 16 MFMAs, k step 32
        f16x8 b = {};
        if (cok) {
            int g = (cc * 64 + mf * 4 + grp) ^ (cc & 7);
            b = *(const f16x8*)(Tw + g * 8);
        }
        acc = __builtin_amdgcn_mfma_f32_16x16x32_f16(areg[mf], b, acc, 0, 0, 0);
    }
    *(f32x4*)Ered[w][lane] = acc;
    __syncthreads();

    // ---- reduce 8 waves, scatter to El[row][col] ----
    if (tid < 64) {
        f32x4 s = {};
#pragma unroll
        for (int ww = 0; ww < 8; ++ww) s += *(const f32x4*)Ered[ww][tid];
        int rr = tid >> 4, c = tid & 15;
#pragma unroll
        for (int r = 0; r < 4; ++r) El[rr * 4 + r][c] = s[r];
    }
    __syncthreads();

    // ---- fused update / final output for this block's 16 rows ----
    if (tid < 64) {
        int b = tid >> 4, r = tid & 15;
        int m = row0 + r, idx = b * NN + m;
        float S0 = El[r][3 * b], S1 = El[r][3 * b + 1], S2 = El[r][3 * b + 2];
        float av = gA[idx], uxv = gUx[idx], uyv = gUy[idx];
        float l = logits[idx] + av * (S0 - uxv * S1 - uyv * S2);
        if (last) {
            out[idx] = l;
        } else {
            float mv = 2.0f / (1.0f + expf(-l)) - 1.0f;
            float t0 = av * mv;
            unsigned short* Td = gTh[rd ^ 1];
            Td[(3 * b + 0) * NN + m] = f16b(t0);
            Td[(3 * b + 1) * NN + m] = f16b(t0 * uxv);
            Td[(3 * b + 2) * NN + m] = f16b(t0 * uyv);
        }
    }
}

extern "C" void kernel_launch(void* const* d_in, const int* in_sizes, int n_in,
                              void* d_out, int out_size, void* d_ws, size_t ws_size,
                              hipStream_t stream) {
    const float* delta_p = (const float*)d_in[0];   // (4,64,64,2)
    const float* logits  = (const float*)d_in[1];   // (4,4096,1)
    const float* W       = (const float*)d_in[2];   // (1,4096,4096)
    float* out = (float*)d_out;

    unsigned* Wb = (unsigned*)d_ws;                  // 32 MiB packed f16 Wsym
    const unsigned short* Wh = (const unsigned short*)d_ws;

    head_kernel<<<WSYM_BLOCKS + 64, 256, 0, stream>>>(W, Wb, delta_p, logits);

    for (int it = 0; it < NITER; ++it)
        matvec_kernel<<<256, TW, 0, stream>>>(Wh, logits, out, it & 1,
                                              it == NITER - 1 ? 1 : 0);
}